// Round 1
// baseline (670.260 us; speedup 1.0000x reference)
//
#include <hip/hip_runtime.h>
#include <hip/hip_bf16.h>

#define C_   32
#define K_   16
#define DLLM 768
#define B_   8
#define L_   512
#define DM   256          // D_MODEL
#define H_   8
#define DK   32
#define G_   256          // H*DK
#define BL   4096         // B*L
#define NN   4096         // C*H*K
#define E_   768
#define TEMPF 0.17677669529663687f

// ---------------------------------------------------------------- K1: kk,v projections
// kk[k,c,g] = topk[c,k,:] . k_proj[c,g,:768] + k_proj[c,g,768]   (stored as kk[c][k][g])
__global__ __launch_bounds__(128) void k1_kv(const float* __restrict__ topk,
                                             const float* __restrict__ kp,
                                             const float* __restrict__ vp,
                                             float* __restrict__ kk,
                                             float* __restrict__ vv) {
    const int c = blockIdx.x;                       // 0..31
    const int g = blockIdx.y * 128 + threadIdx.x;   // 0..255
    __shared__ float t_l[K_][DLLM];                 // 48 KB
    {
        const float* src = topk + (size_t)c * (K_ * DLLM);
        float* dst = &t_l[0][0];
        for (int i = threadIdx.x * 4; i < K_ * DLLM; i += 128 * 4) {
            *reinterpret_cast<float4*>(dst + i) = *reinterpret_cast<const float4*>(src + i);
        }
    }
    __syncthreads();
    const float* kpr = kp + (size_t)(c * G_ + g) * (DLLM + 1);
    const float* vpr = vp + (size_t)(c * G_ + g) * (DLLM + 1);
    float acck[K_], accv[K_];
    const float bk = kpr[DLLM], bv = vpr[DLLM];
#pragma unroll
    for (int k = 0; k < K_; ++k) { acck[k] = bk; accv[k] = bv; }
    for (int d = 0; d < DLLM; d += 4) {
        float4 wk4 = *reinterpret_cast<const float4*>(kpr + d);
        float4 wv4 = *reinterpret_cast<const float4*>(vpr + d);
        const float wk[4] = {wk4.x, wk4.y, wk4.z, wk4.w};
        const float wv[4] = {wv4.x, wv4.y, wv4.z, wv4.w};
#pragma unroll
        for (int dd = 0; dd < 4; ++dd) {
#pragma unroll
            for (int k = 0; k < K_; ++k) {
                acck[k] += wk[dd] * t_l[k][d + dd];
                accv[k] += wv[dd] * t_l[k][d + dd];
            }
        }
    }
#pragma unroll
    for (int k = 0; k < K_; ++k) {
        kk[(size_t)(c * K_ + k) * G_ + g] = acck[k];
        vv[(size_t)(c * K_ + k) * G_ + g] = accv[k];
    }
}

// ---------------------------------------------------------------- K2: A2[m][n], abias[n]
// A[c,h,k,m] = sum_d Wq[c,h*32+d,m] * kk[c][k][h*32+d];  n = (c*8+h)*16+k
__global__ __launch_bounds__(256) void k2_A(const float* __restrict__ qp,
                                            const float* __restrict__ kk,
                                            float* __restrict__ A2,
                                            float* __restrict__ abias) {
    const int c = blockIdx.x, h = blockIdx.y;
    const int m = threadIdx.x;                      // 0..255
    __shared__ float kk_l[K_][DK];
    __shared__ float bq_l[DK];
    for (int i = threadIdx.x; i < K_ * DK; i += 256) {
        int k = i / DK, d = i % DK;
        kk_l[k][d] = kk[(size_t)(c * K_ + k) * G_ + h * DK + d];
    }
    if (threadIdx.x < DK)
        bq_l[threadIdx.x] = qp[(size_t)(c * G_ + h * DK + threadIdx.x) * (DM + 1) + DM];
    __syncthreads();
    float acc[K_];
#pragma unroll
    for (int k = 0; k < K_; ++k) acc[k] = 0.f;
    for (int d = 0; d < DK; ++d) {
        float wq = qp[(size_t)(c * G_ + h * DK + d) * (DM + 1) + m];
#pragma unroll
        for (int k = 0; k < K_; ++k) acc[k] += wq * kk_l[k][d];
    }
    const int ch = c * H_ + h;
#pragma unroll
    for (int k = 0; k < K_; k += 4) {
        float4 v4 = make_float4(acc[k], acc[k + 1], acc[k + 2], acc[k + 3]);
        *reinterpret_cast<float4*>(&A2[(size_t)m * NN + ch * K_ + k]) = v4;
    }
    if (m < K_) {
        float s = 0.f;
#pragma unroll
        for (int d = 0; d < DK; ++d) s += bq_l[d] * kk_l[m][d];
        abias[ch * K_ + m] = s;
    }
}

// ---------------------------------------------------------------- K3: VW[n][e]
// VW[(c*8+h)*16+k][e] = sum_d vv[c][k][h*32+d] * out_w[c,h,d,e]
__global__ __launch_bounds__(768) void k3_VW(const float* __restrict__ ow,
                                             const float* __restrict__ vv,
                                             float* __restrict__ VW) {
    const int c = blockIdx.x, h = blockIdx.y;
    const int e = threadIdx.x;                      // 0..767
    __shared__ float v_l[K_][DK];
    for (int i = threadIdx.x; i < K_ * DK; i += 768) {
        int k = i / DK, d = i % DK;
        v_l[k][d] = vv[(size_t)(c * K_ + k) * G_ + h * DK + d];
    }
    __syncthreads();
    float acc[K_];
#pragma unroll
    for (int k = 0; k < K_; ++k) acc[k] = 0.f;
    for (int d = 0; d < DK; ++d) {
        float w = ow[((size_t)(c * H_ + h) * DK + d) * E_ + e];
#pragma unroll
        for (int k = 0; k < K_; ++k) acc[k] += w * v_l[k][d];
    }
    const int ch = c * H_ + h;
#pragma unroll
    for (int k = 0; k < K_; ++k)
        VW[(size_t)(ch * K_ + k) * E_ + e] = acc[k];
}

// ---------------------------------------------------------------- K4: P = p * softmax(TEMP*(ts@A2 + abias))
// logits GEMM: (4096 x 256) @ (256 x 4096); block tile 64(bl) x 256(n); thread: 4 bl x 16 n (one k-group)
__device__ __forceinline__ int swz(int col) { return col ^ (((col >> 4) & 7) << 2); }

__global__ __launch_bounds__(256) void k4_att(const float* __restrict__ ts,
                                              const float* __restrict__ A2,
                                              const float* __restrict__ abias,
                                              const float* __restrict__ probs,
                                              float* __restrict__ P) {
    const int bl0 = blockIdx.x * 64;
    const int n0  = blockIdx.y * 256;
    const int t = threadIdx.x;
    const int tl = t >> 4, tn = t & 15;
    __shared__ float ts_l[64][20];          // pad 20: 2-way max on reads, float4-aligned
    __shared__ float a_l[16 * 256];         // XOR-swizzled
    float acc[4][16];
#pragma unroll
    for (int i = 0; i < 4; ++i)
#pragma unroll
        for (int k = 0; k < 16; ++k) acc[i][k] = 0.f;

    for (int m0 = 0; m0 < DM; m0 += 16) {
        {   // ts tile: 64 x 16
            int row = t >> 2, c4 = (t & 3) * 4;
            float4 v = *reinterpret_cast<const float4*>(&ts[(size_t)(bl0 + row) * DM + m0 + c4]);
            *reinterpret_cast<float4*>(&ts_l[row][c4]) = v;
        }
        {   // A2 tile: 16 x 256, swizzled store
            int j = t >> 4, base = (t & 15) * 16;
            const float* src = &A2[(size_t)(m0 + j) * NN + n0 + base];
#pragma unroll
            for (int w = 0; w < 4; ++w) {
                int col = base + w * 4;
                *reinterpret_cast<float4*>(&a_l[j * 256 + swz(col)]) =
                    *reinterpret_cast<const float4*>(src + w * 4);
            }
        }
        __syncthreads();
#pragma unroll
        for (int j = 0; j < 16; ++j) {
            float av[16];
#pragma unroll
            for (int w = 0; w < 4; ++w) {
                int col = tn * 16 + w * 4;
                float4 v4 = *reinterpret_cast<const float4*>(&a_l[j * 256 + swz(col)]);
                av[w * 4 + 0] = v4.x; av[w * 4 + 1] = v4.y;
                av[w * 4 + 2] = v4.z; av[w * 4 + 3] = v4.w;
            }
#pragma unroll
            for (int i = 0; i < 4; ++i) {
                float tv = ts_l[tl * 4 + i][j];
#pragma unroll
                for (int k = 0; k < 16; ++k) acc[i][k] += tv * av[k];
            }
        }
        __syncthreads();
    }
    // epilogue: bias, softmax over the 16-k group, scale by cluster prob
    const int grp = (n0 >> 4) + tn;     // global (c*8+h)
    const int cc = grp >> 3;
    float ab[16];
#pragma unroll
    for (int k = 0; k < 16; ++k) ab[k] = abias[grp * 16 + k];
#pragma unroll
    for (int i = 0; i < 4; ++i) {
        const int bl = bl0 + tl * 4 + i;
        float z[16], mx = -1e30f;
#pragma unroll
        for (int k = 0; k < 16; ++k) {
            z[k] = TEMPF * (acc[i][k] + ab[k]);
            mx = fmaxf(mx, z[k]);
        }
        float s = 0.f;
#pragma unroll
        for (int k = 0; k < 16; ++k) { z[k] = __expf(z[k] - mx); s += z[k]; }
        const float pv = probs[(size_t)bl * C_ + cc] / s;
#pragma unroll
        for (int k = 0; k < 16; k += 4) {
            float4 v4 = make_float4(z[k] * pv, z[k + 1] * pv, z[k + 2] * pv, z[k + 3] * pv);
            *reinterpret_cast<float4*>(&P[(size_t)bl * NN + grp * 16 + k]) = v4;
        }
    }
}

// ---------------------------------------------------------------- K5: out = P @ VW + probs @ out_b
// (4096 x 4096) @ (4096 x 768); block tile 64(bl) x 128(e); thread: 4 bl x 8 e (e strided: te*4 and 64+te*4)
__global__ __launch_bounds__(256) void k5_out(const float* __restrict__ P,
                                              const float* __restrict__ VW,
                                              const float* __restrict__ probs,
                                              const float* __restrict__ outb,
                                              float* __restrict__ out) {
    const int bl0 = blockIdx.x * 64;
    const int e0  = blockIdx.y * 128;
    const int t = threadIdx.x;
    const int tl = t >> 4, te = t & 15;
    __shared__ float P_l[64][36];           // pad 36: float4-aligned rows, 2-way max
    __shared__ float VW_l[32 * 132];        // pad 132
    float acc[4][8];
#pragma unroll
    for (int i = 0; i < 4; ++i)
#pragma unroll
        for (int w = 0; w < 8; ++w) acc[i][w] = 0.f;

    for (int n0 = 0; n0 < NN; n0 += 32) {
        {   // P tile 64 x 32
            int row = t >> 3, c4 = (t & 7) * 4;
            *reinterpret_cast<float4*>(&P_l[row][c4]) =
                *reinterpret_cast<const float4*>(&P[(size_t)(bl0 + row) * NN + n0 + c4]);
            *reinterpret_cast<float4*>(&P_l[row + 32][c4]) =
                *reinterpret_cast<const float4*>(&P[(size_t)(bl0 + row + 32) * NN + n0 + c4]);
        }
        {   // VW tile 32 x 128
            int j = t >> 3, base = (t & 7) * 16;
            const float* src = &VW[(size_t)(n0 + j) * E_ + e0 + base];
#pragma unroll
            for (int w = 0; w < 4; ++w)
                *reinterpret_cast<float4*>(&VW_l[j * 132 + base + w * 4]) =
                    *reinterpret_cast<const float4*>(src + w * 4);
        }
        __syncthreads();
#pragma unroll 8
        for (int j = 0; j < 32; ++j) {
            float4 e_lo = *reinterpret_cast<const float4*>(&VW_l[j * 132 + te * 4]);
            float4 e_hi = *reinterpret_cast<const float4*>(&VW_l[j * 132 + 64 + te * 4]);
            const float ev[8] = {e_lo.x, e_lo.y, e_lo.z, e_lo.w, e_hi.x, e_hi.y, e_hi.z, e_hi.w};
#pragma unroll
            for (int i = 0; i < 4; ++i) {
                float pvv = P_l[tl * 4 + i][j];
#pragma unroll
                for (int w = 0; w < 8; ++w) acc[i][w] += pvv * ev[w];
            }
        }
        __syncthreads();
    }
    // epilogue: += probs @ out_b
    for (int c = 0; c < C_; ++c) {
        float4 ob0 = *reinterpret_cast<const float4*>(&outb[(size_t)c * E_ + e0 + te * 4]);
        float4 ob1 = *reinterpret_cast<const float4*>(&outb[(size_t)c * E_ + e0 + 64 + te * 4]);
#pragma unroll
        for (int i = 0; i < 4; ++i) {
            float pb = probs[(size_t)(bl0 + tl * 4 + i) * C_ + c];
            acc[i][0] += pb * ob0.x; acc[i][1] += pb * ob0.y;
            acc[i][2] += pb * ob0.z; acc[i][3] += pb * ob0.w;
            acc[i][4] += pb * ob1.x; acc[i][5] += pb * ob1.y;
            acc[i][6] += pb * ob1.z; acc[i][7] += pb * ob1.w;
        }
    }
#pragma unroll
    for (int i = 0; i < 4; ++i) {
        const int bl = bl0 + tl * 4 + i;
        *reinterpret_cast<float4*>(&out[(size_t)bl * E_ + e0 + te * 4]) =
            make_float4(acc[i][0], acc[i][1], acc[i][2], acc[i][3]);
        *reinterpret_cast<float4*>(&out[(size_t)bl * E_ + e0 + 64 + te * 4]) =
            make_float4(acc[i][4], acc[i][5], acc[i][6], acc[i][7]);
    }
}

// ----------------------------------------------------------------
extern "C" void kernel_launch(void* const* d_in, const int* in_sizes, int n_in,
                              void* d_out, int out_size, void* d_ws, size_t ws_size,
                              hipStream_t stream) {
    const float* topk  = (const float*)d_in[0];   // (32,16,768)
    const float* ts    = (const float*)d_in[1];   // (8,512,256)
    const float* probs = (const float*)d_in[2];   // (8,512,32)
    const float* qp    = (const float*)d_in[3];   // (32,256,257)
    const float* kp    = (const float*)d_in[4];   // (32,256,769)
    const float* vp    = (const float*)d_in[5];   // (32,256,769)
    const float* ow    = (const float*)d_in[6];   // (32,8,32,768)
    const float* ob    = (const float*)d_in[7];   // (32,768)
    float* out = (float*)d_out;                   // (4096,768)

    float* ws = (float*)d_ws;
    float* kk = ws;                     // 131072
    float* vv = kk + 131072;            // 131072
    float* A2 = vv + 131072;            // 1048576  [m][n]
    float* ab = A2 + 1048576;           // 4096
    float* VW = ab + 4096;              // 3145728  [n][e]
    float* P  = VW + 3145728;           // 16777216 [bl][n]

    k1_kv <<<dim3(32, 2),  128, 0, stream>>>(topk, kp, vp, kk, vv);
    k2_A  <<<dim3(32, 8),  256, 0, stream>>>(qp, kk, A2, ab);
    k3_VW <<<dim3(32, 8),  768, 0, stream>>>(ow, vv, VW);
    k4_att<<<dim3(64, 16), 256, 0, stream>>>(ts, A2, ab, probs, P);
    k5_out<<<dim3(64, 6),  256, 0, stream>>>(P, VW, probs, ob, out);
}

// Round 2
// 220.916 us; speedup vs baseline: 3.0340x; 3.0340x over previous
//
#include <hip/hip_runtime.h>
#include <hip/hip_bf16.h>

#define C_   32
#define K_   16
#define DLLM 768
#define DM   256
#define H_   8
#define DK   32
#define G_   256
#define BL   4096
#define NN   4096
#define E_   768
#define LDP  4128          // P / VWt row stride: 4096 + 32 bias-fold columns
#define TEMPF 0.17677669529663687f

typedef __attribute__((ext_vector_type(8))) short bf16x8;
typedef __attribute__((ext_vector_type(4))) float f32x4;

__device__ __forceinline__ unsigned short f2bf(float f) {
    unsigned int u = __float_as_uint(f);
    unsigned int r = (u + 0x7fffu + ((u >> 16) & 1u)) >> 16;
    return (unsigned short)r;
}

// ---------------------------------------------------------------- K1: kk,v projections (fp32, unchanged)
__global__ __launch_bounds__(128) void k1_kv(const float* __restrict__ topk,
                                             const float* __restrict__ kp,
                                             const float* __restrict__ vp,
                                             float* __restrict__ kk,
                                             float* __restrict__ vv) {
    const int c = blockIdx.x;
    const int g = blockIdx.y * 128 + threadIdx.x;
    __shared__ float t_l[K_][DLLM];
    {
        const float* src = topk + (size_t)c * (K_ * DLLM);
        float* dst = &t_l[0][0];
        for (int i = threadIdx.x * 4; i < K_ * DLLM; i += 128 * 4)
            *reinterpret_cast<float4*>(dst + i) = *reinterpret_cast<const float4*>(src + i);
    }
    __syncthreads();
    const float* kpr = kp + (size_t)(c * G_ + g) * (DLLM + 1);
    const float* vpr = vp + (size_t)(c * G_ + g) * (DLLM + 1);
    float acck[K_], accv[K_];
    const float bk = kpr[DLLM], bv = vpr[DLLM];
#pragma unroll
    for (int k = 0; k < K_; ++k) { acck[k] = bk; accv[k] = bv; }
    for (int d = 0; d < DLLM; d += 4) {
        float4 wk4 = *reinterpret_cast<const float4*>(kpr + d);
        float4 wv4 = *reinterpret_cast<const float4*>(vpr + d);
        const float wk[4] = {wk4.x, wk4.y, wk4.z, wk4.w};
        const float wv[4] = {wv4.x, wv4.y, wv4.z, wv4.w};
#pragma unroll
        for (int dd = 0; dd < 4; ++dd)
#pragma unroll
            for (int k = 0; k < K_; ++k) {
                acck[k] += wk[dd] * t_l[k][d + dd];
                accv[k] += wv[dd] * t_l[k][d + dd];
            }
    }
#pragma unroll
    for (int k = 0; k < K_; ++k) {
        kk[(size_t)(c * K_ + k) * G_ + g] = acck[k];
        vv[(size_t)(c * K_ + k) * G_ + g] = accv[k];
    }
}

// ---------------------------------------------------------------- k0: ts->bf16 + bias-fold columns of P and VWt
__global__ __launch_bounds__(256) void k0_cvt(const float* __restrict__ ts,
                                              const float* __restrict__ probs,
                                              const float* __restrict__ outb,
                                              unsigned short* __restrict__ tsb,
                                              unsigned short* __restrict__ P,
                                              unsigned short* __restrict__ VWt) {
    const int bid = blockIdx.x, t = threadIdx.x;
    if (bid < 1024) {                              // ts (4096x256) -> bf16
        const int idx = bid * 1024 + t * 4;
        float4 v = *reinterpret_cast<const float4*>(ts + idx);
        uint2 o;
        o.x = f2bf(v.x) | ((unsigned)f2bf(v.y) << 16);
        o.y = f2bf(v.z) | ((unsigned)f2bf(v.w) << 16);
        *reinterpret_cast<uint2*>(tsb + idx) = o;
    } else if (bid < 1056) {                       // P[:,4096+c] = probs[bl][c]
        const int b2 = bid - 1024;
        const int row = b2 * 128 + (t >> 1);
        const int ch = (t & 1) * 16;
        unsigned short o[16];
#pragma unroll
        for (int j = 0; j < 16; ++j) o[j] = f2bf(probs[row * 32 + ch + j]);
        uint4 u0, u1;
        u0.x = o[0] | (o[1] << 16);  u0.y = o[2] | (o[3] << 16);
        u0.z = o[4] | (o[5] << 16);  u0.w = o[6] | (o[7] << 16);
        u1.x = o[8] | (o[9] << 16);  u1.y = o[10] | (o[11] << 16);
        u1.z = o[12] | (o[13] << 16); u1.w = o[14] | (o[15] << 16);
        unsigned short* dst = P + (size_t)row * LDP + 4096 + ch;
        *reinterpret_cast<uint4*>(dst) = u0;
        *reinterpret_cast<uint4*>(dst + 8) = u1;
    } else {                                       // VWt[e][4096+c] = outb[c][e]
        const int idx = (bid - 1056) * 256 + t;    // 768*32 = 24576
        const int e = idx >> 5, cc = idx & 31;
        VWt[(size_t)e * LDP + 4096 + cc] = f2bf(outb[cc * E_ + e]);
    }
}

// ---------------------------------------------------------------- K2: A2t[n][m] bf16, abias[n] fp32
__global__ __launch_bounds__(256) void k2_A(const float* __restrict__ qp,
                                            const float* __restrict__ kk,
                                            unsigned short* __restrict__ A2t,
                                            float* __restrict__ abias) {
    const int c = blockIdx.x, h = blockIdx.y;
    const int m = threadIdx.x;
    __shared__ float kk_l[K_][DK];
    __shared__ float bq_l[DK];
    for (int i = threadIdx.x; i < K_ * DK; i += 256) {
        int k = i / DK, d = i % DK;
        kk_l[k][d] = kk[(size_t)(c * K_ + k) * G_ + h * DK + d];
    }
    if (threadIdx.x < DK)
        bq_l[threadIdx.x] = qp[(size_t)(c * G_ + h * DK + threadIdx.x) * (DM + 1) + DM];
    __syncthreads();
    float acc[K_];
#pragma unroll
    for (int k = 0; k < K_; ++k) acc[k] = 0.f;
    for (int d = 0; d < DK; ++d) {
        float wq = qp[(size_t)(c * G_ + h * DK + d) * (DM + 1) + m];
#pragma unroll
        for (int k = 0; k < K_; ++k) acc[k] += wq * kk_l[k][d];
    }
    const int ch = c * H_ + h;
#pragma unroll
    for (int k = 0; k < K_; ++k)
        A2t[(size_t)(ch * 16 + k) * DM + m] = f2bf(acc[k]);
    if (m < K_) {
        float s = 0.f;
#pragma unroll
        for (int d = 0; d < DK; ++d) s += bq_l[d] * kk_l[m][d];
        abias[ch * 16 + m] = s;
    }
}

// ---------------------------------------------------------------- K3: VWt[e][n] bf16
__global__ __launch_bounds__(768) void k3_VW(const float* __restrict__ ow,
                                             const float* __restrict__ vv,
                                             unsigned short* __restrict__ VWt) {
    const int c = blockIdx.x, h = blockIdx.y;
    const int e = threadIdx.x;
    __shared__ float v_l[K_][DK];
    for (int i = threadIdx.x; i < K_ * DK; i += 768) {
        int k = i / DK, d = i % DK;
        v_l[k][d] = vv[(size_t)(c * K_ + k) * G_ + h * DK + d];
    }
    __syncthreads();
    float acc[K_];
#pragma unroll
    for (int k = 0; k < K_; ++k) acc[k] = 0.f;
    for (int d = 0; d < DK; ++d) {
        float w = ow[((size_t)(c * H_ + h) * DK + d) * E_ + e];
#pragma unroll
        for (int k = 0; k < K_; ++k) acc[k] += w * v_l[k][d];
    }
    const int ch = c * H_ + h;
#pragma unroll
    for (int k = 0; k < K_; ++k)
        VWt[(size_t)e * LDP + ch * 16 + k] = f2bf(acc[k]);
}

// ---------------------------------------------------------------- K4: MFMA logits + softmax + prob scale -> P bf16
// D[n][bl] = A2t[n][m] . tsb[bl][m];  128x128 tile, BK=32, 4 waves (2x2), acc[4][4]
__global__ __launch_bounds__(256) void k4_att(const unsigned short* __restrict__ A2t,
                                              const unsigned short* __restrict__ tsb,
                                              const float* __restrict__ abias,
                                              const float* __restrict__ probs,
                                              unsigned short* __restrict__ P) {
    const int n0  = blockIdx.x * 128;
    const int bl0 = blockIdx.y * 128;
    const int t = threadIdx.x;
    const int lane = t & 63, w = t >> 6;
    const int wr = w >> 1, wc = w & 1;
    const int c = lane & 15, g = lane >> 4;

    __shared__ unsigned short a_l[128 * 32];
    __shared__ unsigned short b_l[128 * 32];
    __shared__ float ab_l[128];
    __shared__ float pb_l[128];

    if (t < 128) {
        ab_l[t] = abias[n0 + t];
        pb_l[t] = probs[(size_t)(bl0 + t) * C_ + (n0 >> 7)];
    }

    const int srow = t >> 1, soff = (t & 1) * 16;   // staging: 16 bf16 per thread per tile
    const unsigned short* gA = A2t + (size_t)(n0 + srow) * DM + soff;
    const unsigned short* gB = tsb + (size_t)(bl0 + srow) * DM + soff;

    f32x4 acc[4][4] = {};
    uint4 ra0, ra1, rb0, rb1;

    ra0 = *reinterpret_cast<const uint4*>(gA);
    ra1 = *reinterpret_cast<const uint4*>(gA + 8);
    rb0 = *reinterpret_cast<const uint4*>(gB);
    rb1 = *reinterpret_cast<const uint4*>(gB + 8);

    for (int kt = 0; kt < 8; ++kt) {
        __syncthreads();
        *reinterpret_cast<uint4*>(&a_l[t * 16])     = ra0;
        *reinterpret_cast<uint4*>(&a_l[t * 16 + 8]) = ra1;
        *reinterpret_cast<uint4*>(&b_l[t * 16])     = rb0;
        *reinterpret_cast<uint4*>(&b_l[t * 16 + 8]) = rb1;
        __syncthreads();
        if (kt < 7) {
            ra0 = *reinterpret_cast<const uint4*>(gA + (kt + 1) * 32);
            ra1 = *reinterpret_cast<const uint4*>(gA + (kt + 1) * 32 + 8);
            rb0 = *reinterpret_cast<const uint4*>(gB + (kt + 1) * 32);
            rb1 = *reinterpret_cast<const uint4*>(gB + (kt + 1) * 32 + 8);
        }
        bf16x8 af[4], bfr[4];
#pragma unroll
        for (int a = 0; a < 4; ++a)
            af[a] = *reinterpret_cast<const bf16x8*>(&a_l[(wr * 64 + a * 16 + c) * 32 + g * 8]);
#pragma unroll
        for (int b = 0; b < 4; ++b)
            bfr[b] = *reinterpret_cast<const bf16x8*>(&b_l[(wc * 64 + b * 16 + c) * 32 + g * 8]);
#pragma unroll
        for (int a = 0; a < 4; ++a)
#pragma unroll
            for (int b = 0; b < 4; ++b)
                acc[a][b] = __builtin_amdgcn_mfma_f32_16x16x32_bf16(af[a], bfr[b], acc[a][b], 0, 0, 0);
    }

    // epilogue: z = TEMP*(acc+abias); softmax over the 16 rows of each frag; scale by prob; write bf16
#pragma unroll
    for (int a = 0; a < 4; ++a) {
        const int nbase = wr * 64 + a * 16 + g * 4;
#pragma unroll
        for (int b = 0; b < 4; ++b) {
            const int bll = wc * 64 + b * 16 + c;
            float z[4], mx = -1e30f;
#pragma unroll
            for (int i = 0; i < 4; ++i) {
                z[i] = TEMPF * (acc[a][b][i] + ab_l[nbase + i]);
                mx = fmaxf(mx, z[i]);
            }
            mx = fmaxf(mx, __shfl_xor(mx, 16));
            mx = fmaxf(mx, __shfl_xor(mx, 32));
            float s = 0.f;
#pragma unroll
            for (int i = 0; i < 4; ++i) { z[i] = __expf(z[i] - mx); s += z[i]; }
            s += __shfl_xor(s, 16);
            s += __shfl_xor(s, 32);
            const float pv = pb_l[bll] / s;
            uint2 o;
            o.x = f2bf(z[0] * pv) | ((unsigned)f2bf(z[1] * pv) << 16);
            o.y = f2bf(z[2] * pv) | ((unsigned)f2bf(z[3] * pv) << 16);
            *reinterpret_cast<uint2*>(P + (size_t)(bl0 + bll) * LDP + n0 + nbase) = o;
        }
    }
}

// ---------------------------------------------------------------- K5: part[ks] = P(blx(2048|2080)) @ VWt^T
// M=bl (BM=64), N=e (BN=128), K split in 2; 4 waves (2x2), wave 32x64, acc[2][4]
__global__ __launch_bounds__(256) void k5_out(const unsigned short* __restrict__ P,
                                              const unsigned short* __restrict__ VWt,
                                              float* __restrict__ part) {
    const int bl0 = blockIdx.x * 64;
    const int e0  = blockIdx.y * 128;
    const int ks  = blockIdx.z;
    const int t = threadIdx.x;
    const int lane = t & 63, w = t >> 6;
    const int wr = w >> 1, wc = w & 1;
    const int c = lane & 15, g = lane >> 4;

    __shared__ unsigned short a_l[64 * 32];
    __shared__ unsigned short b_l[128 * 32];

    const int nstart = ks * 2048;
    const int nsteps = 64 + ks;        // ks1 covers the 32 bias-fold columns too

    const int arow = t >> 2, aoff = (t & 3) * 8;    // A: 8 bf16 per thread
    const int brow = t >> 1, boff = (t & 1) * 16;   // B: 16 bf16 per thread
    const unsigned short* gA = P   + (size_t)(bl0 + arow) * LDP + nstart + aoff;
    const unsigned short* gB = VWt + (size_t)(e0 + brow) * LDP + nstart + boff;

    f32x4 acc[2][4] = {};
    uint4 ra, rb0, rb1;
    ra  = *reinterpret_cast<const uint4*>(gA);
    rb0 = *reinterpret_cast<const uint4*>(gB);
    rb1 = *reinterpret_cast<const uint4*>(gB + 8);

    for (int kt = 0; kt < nsteps; ++kt) {
        __syncthreads();
        *reinterpret_cast<uint4*>(&a_l[t * 8])      = ra;
        *reinterpret_cast<uint4*>(&b_l[t * 16])     = rb0;
        *reinterpret_cast<uint4*>(&b_l[t * 16 + 8]) = rb1;
        __syncthreads();
        if (kt + 1 < nsteps) {
            ra  = *reinterpret_cast<const uint4*>(gA + (kt + 1) * 32);
            rb0 = *reinterpret_cast<const uint4*>(gB + (kt + 1) * 32);
            rb1 = *reinterpret_cast<const uint4*>(gB + (kt + 1) * 32 + 8);
        }
        bf16x8 af[2], bfr[4];
#pragma unroll
        for (int a = 0; a < 2; ++a)
            af[a] = *reinterpret_cast<const bf16x8*>(&a_l[(wr * 32 + a * 16 + c) * 32 + g * 8]);
#pragma unroll
        for (int b = 0; b < 4; ++b)
            bfr[b] = *reinterpret_cast<const bf16x8*>(&b_l[(wc * 64 + b * 16 + c) * 32 + g * 8]);
#pragma unroll
        for (int a = 0; a < 2; ++a)
#pragma unroll
            for (int b = 0; b < 4; ++b)
                acc[a][b] = __builtin_amdgcn_mfma_f32_16x16x32_bf16(af[a], bfr[b], acc[a][b], 0, 0, 0);
    }

    float* pp = part + ((size_t)ks * BL + bl0) * E_ + e0;
#pragma unroll
    for (int a = 0; a < 2; ++a)
#pragma unroll
        for (int b = 0; b < 4; ++b)
#pragma unroll
            for (int i = 0; i < 4; ++i)
                pp[(size_t)(wr * 32 + a * 16 + g * 4 + i) * E_ + wc * 64 + b * 16 + c] = acc[a][b][i];
}

// ---------------------------------------------------------------- k6: out = part0 + part1
__global__ __launch_bounds__(256) void k6_red(const float* __restrict__ part,
                                              float* __restrict__ out) {
    const int idx = (blockIdx.x * 256 + threadIdx.x) * 4;
    float4 p0 = *reinterpret_cast<const float4*>(part + idx);
    float4 p1 = *reinterpret_cast<const float4*>(part + (size_t)BL * E_ + idx);
    float4 o = make_float4(p0.x + p1.x, p0.y + p1.y, p0.z + p1.z, p0.w + p1.w);
    *reinterpret_cast<float4*>(out + idx) = o;
}

// ----------------------------------------------------------------
extern "C" void kernel_launch(void* const* d_in, const int* in_sizes, int n_in,
                              void* d_out, int out_size, void* d_ws, size_t ws_size,
                              hipStream_t stream) {
    const float* topk  = (const float*)d_in[0];
    const float* ts    = (const float*)d_in[1];
    const float* probs = (const float*)d_in[2];
    const float* qp    = (const float*)d_in[3];
    const float* kp    = (const float*)d_in[4];
    const float* vp    = (const float*)d_in[5];
    const float* ow    = (const float*)d_in[6];
    const float* ob    = (const float*)d_in[7];
    float* out = (float*)d_out;

    char* wp = (char*)d_ws;
    float* kk            = (float*)wp;           wp += 524288;
    float* vv            = (float*)wp;           wp += 524288;
    float* ab            = (float*)wp;           wp += 16384;
    unsigned short* tsb  = (unsigned short*)wp;  wp += 2097152;
    unsigned short* A2t  = (unsigned short*)wp;  wp += 2097152;
    unsigned short* VWt  = (unsigned short*)wp;  wp += (size_t)E_ * LDP * 2;   // 6,340,608
    unsigned short* P    = (unsigned short*)wp;  wp += (size_t)BL * LDP * 2;   // 33,816,576
    float* part          = (float*)wp;           // 2 * 4096*768*4 = 25,165,824

    k1_kv <<<dim3(32, 2),   128, 0, stream>>>(topk, kp, vp, kk, vv);
    k0_cvt<<<1152,          256, 0, stream>>>(ts, probs, ob, tsb, P, VWt);
    k2_A  <<<dim3(32, 8),   256, 0, stream>>>(qp, kk, A2t, ab);
    k3_VW <<<dim3(32, 8),   768, 0, stream>>>(ow, vv, VWt);
    k4_att<<<dim3(32, 32),  256, 0, stream>>>(A2t, tsb, ab, probs, P);
    k5_out<<<dim3(64, 6, 2),256, 0, stream>>>(P, VWt, part);
    k6_red<<<3072,          256, 0, stream>>>(part, out);
}

// Round 3
// 145.059 us; speedup vs baseline: 4.6206x; 1.5229x over previous
//
#include <hip/hip_runtime.h>
#include <hip/hip_bf16.h>

#define C_   32
#define K_   16
#define DLLM 768
#define DM   256
#define H_   8
#define DK   32
#define G_   256
#define BL   4096
#define NN   4096
#define E_   768
#define LDP  4128          // P / VWt row stride: 4096 + 32 bias-fold columns
#define TEMPF 0.17677669529663687f

typedef __attribute__((ext_vector_type(8))) short bf16x8;
typedef __attribute__((ext_vector_type(4))) float f32x4;

__device__ __forceinline__ unsigned short f2bf(float f) {
    unsigned int u = __float_as_uint(f);
    unsigned int r = (u + 0x7fffu + ((u >> 16) & 1u)) >> 16;
    return (unsigned short)r;
}

// ---------------------------------------------------------------- K1: kk,v partial projections (d-split x8)
// partk[c][dc][k][g] = sum_{d in chunk dc} topk[c,k,d] * kp[c,g,d]
__global__ __launch_bounds__(256) void k1_kv(const float* __restrict__ topk,
                                             const float* __restrict__ kp,
                                             const float* __restrict__ vp,
                                             float* __restrict__ partk,
                                             float* __restrict__ partv) {
    const int c  = blockIdx.x;          // 0..31
    const int dc = blockIdx.y;          // 0..7
    const int d0 = dc * 96;
    const int g  = threadIdx.x;         // 0..255
    __shared__ float t_l[K_][96];       // 6 KB
    for (int i = threadIdx.x; i < 384; i += 256) {
        int k = i / 24, c4 = (i % 24) * 4;
        *reinterpret_cast<float4*>(&t_l[k][c4]) =
            *reinterpret_cast<const float4*>(topk + (size_t)(c * K_ + k) * DLLM + d0 + c4);
    }
    __syncthreads();
    const float* kpr = kp + (size_t)(c * G_ + g) * (DLLM + 1) + d0;
    const float* vpr = vp + (size_t)(c * G_ + g) * (DLLM + 1) + d0;
    float acck[K_] = {}, accv[K_] = {};
    for (int d = 0; d < 96; d += 4) {
        float4 wk4 = *reinterpret_cast<const float4*>(kpr + d);
        float4 wv4 = *reinterpret_cast<const float4*>(vpr + d);
        const float wk[4] = {wk4.x, wk4.y, wk4.z, wk4.w};
        const float wv[4] = {wv4.x, wv4.y, wv4.z, wv4.w};
#pragma unroll
        for (int dd = 0; dd < 4; ++dd)
#pragma unroll
            for (int k = 0; k < K_; ++k) {
                acck[k] += wk[dd] * t_l[k][d + dd];
                accv[k] += wv[dd] * t_l[k][d + dd];
            }
    }
    float* pk = partk + ((size_t)(c * 8 + dc) * K_) * G_ + g;
    float* pv = partv + ((size_t)(c * 8 + dc) * K_) * G_ + g;
#pragma unroll
    for (int k = 0; k < K_; ++k) {
        pk[k * G_] = acck[k];
        pv[k * G_] = accv[k];
    }
}

// ---------------------------------------------------------------- K1r: kk/vv = sum partials + bias
__global__ __launch_bounds__(256) void k1r(const float* __restrict__ partk,
                                           const float* __restrict__ partv,
                                           const float* __restrict__ kp,
                                           const float* __restrict__ vp,
                                           float* __restrict__ kk,
                                           float* __restrict__ vv) {
    const int idx = blockIdx.x * 256 + threadIdx.x;   // (c*16+k)*256+g
    const int g = idx & 255, rest = idx >> 8;
    const int k = rest & 15, c = rest >> 4;
    float sk = kp[(size_t)(c * G_ + g) * (DLLM + 1) + DLLM];
    float sv = vp[(size_t)(c * G_ + g) * (DLLM + 1) + DLLM];
#pragma unroll
    for (int dc = 0; dc < 8; ++dc) {
        sk += partk[((size_t)(c * 8 + dc) * K_ + k) * G_ + g];
        sv += partv[((size_t)(c * 8 + dc) * K_ + k) * G_ + g];
    }
    kk[idx] = sk;
    vv[idx] = sv;
}

// ---------------------------------------------------------------- k0: ts->bf16 + bias-fold columns of P and VWt
__global__ __launch_bounds__(256) void k0_cvt(const float* __restrict__ ts,
                                              const float* __restrict__ probs,
                                              const float* __restrict__ outb,
                                              unsigned short* __restrict__ tsb,
                                              unsigned short* __restrict__ P,
                                              unsigned short* __restrict__ VWt) {
    const int bid = blockIdx.x, t = threadIdx.x;
    if (bid < 1024) {                              // ts (4096x256) -> bf16
        const int idx = bid * 1024 + t * 4;
        float4 v = *reinterpret_cast<const float4*>(ts + idx);
        uint2 o;
        o.x = f2bf(v.x) | ((unsigned)f2bf(v.y) << 16);
        o.y = f2bf(v.z) | ((unsigned)f2bf(v.w) << 16);
        *reinterpret_cast<uint2*>(tsb + idx) = o;
    } else if (bid < 1056) {                       // P[:,4096+c] = probs[bl][c]
        const int b2 = bid - 1024;
        const int row = b2 * 128 + (t >> 1);
        const int ch = (t & 1) * 16;
        unsigned short o[16];
#pragma unroll
        for (int j = 0; j < 16; ++j) o[j] = f2bf(probs[row * 32 + ch + j]);
        uint4 u0, u1;
        u0.x = o[0] | (o[1] << 16);  u0.y = o[2] | (o[3] << 16);
        u0.z = o[4] | (o[5] << 16);  u0.w = o[6] | (o[7] << 16);
        u1.x = o[8] | (o[9] << 16);  u1.y = o[10] | (o[11] << 16);
        u1.z = o[12] | (o[13] << 16); u1.w = o[14] | (o[15] << 16);
        unsigned short* dst = P + (size_t)row * LDP + 4096 + ch;
        *reinterpret_cast<uint4*>(dst) = u0;
        *reinterpret_cast<uint4*>(dst + 8) = u1;
    } else {                                       // VWt[e][4096+c] = outb[c][e]
        const int idx = (bid - 1056) * 256 + t;    // 768*32 = 24576
        const int e = idx >> 5, cc = idx & 31;
        VWt[(size_t)e * LDP + 4096 + cc] = f2bf(outb[cc * E_ + e]);
    }
}

// ---------------------------------------------------------------- K2: A2t[n][m] bf16, abias[n] fp32
__global__ __launch_bounds__(256) void k2_A(const float* __restrict__ qp,
                                            const float* __restrict__ kk,
                                            unsigned short* __restrict__ A2t,
                                            float* __restrict__ abias) {
    const int c = blockIdx.x, h = blockIdx.y;
    const int m = threadIdx.x;
    __shared__ float kk_l[K_][DK];
    __shared__ float bq_l[DK];
    for (int i = threadIdx.x; i < K_ * DK; i += 256) {
        int k = i / DK, d = i % DK;
        kk_l[k][d] = kk[(size_t)(c * K_ + k) * G_ + h * DK + d];
    }
    if (threadIdx.x < DK)
        bq_l[threadIdx.x] = qp[(size_t)(c * G_ + h * DK + threadIdx.x) * (DM + 1) + DM];
    __syncthreads();
    float acc[K_];
#pragma unroll
    for (int k = 0; k < K_; ++k) acc[k] = 0.f;
    for (int d = 0; d < DK; ++d) {
        float wq = qp[(size_t)(c * G_ + h * DK + d) * (DM + 1) + m];
#pragma unroll
        for (int k = 0; k < K_; ++k) acc[k] += wq * kk_l[k][d];
    }
    const int ch = c * H_ + h;
#pragma unroll
    for (int k = 0; k < K_; ++k)
        A2t[(size_t)(ch * 16 + k) * DM + m] = f2bf(acc[k]);
    if (m < K_) {
        float s = 0.f;
#pragma unroll
        for (int d = 0; d < DK; ++d) s += bq_l[d] * kk_l[m][d];
        abias[ch * 16 + m] = s;
    }
}

// ---------------------------------------------------------------- K3: VWt[e][n] bf16
__global__ __launch_bounds__(768) void k3_VW(const float* __restrict__ ow,
                                             const float* __restrict__ vv,
                                             unsigned short* __restrict__ VWt) {
    const int c = blockIdx.x, h = blockIdx.y;
    const int e = threadIdx.x;
    __shared__ float v_l[K_][DK];
    for (int i = threadIdx.x; i < K_ * DK; i += 768) {
        int k = i / DK, d = i % DK;
        v_l[k][d] = vv[(size_t)(c * K_ + k) * G_ + h * DK + d];
    }
    __syncthreads();
    float acc[K_];
#pragma unroll
    for (int k = 0; k < K_; ++k) acc[k] = 0.f;
    for (int d = 0; d < DK; ++d) {
        float w = ow[((size_t)(c * H_ + h) * DK + d) * E_ + e];
#pragma unroll
        for (int k = 0; k < K_; ++k) acc[k] += w * v_l[k][d];
    }
    const int ch = c * H_ + h;
#pragma unroll
    for (int k = 0; k < K_; ++k)
        VWt[(size_t)e * LDP + ch * 16 + k] = f2bf(acc[k]);
}

// ---------------------------------------------------------------- K4: MFMA logits + softmax + prob scale -> P bf16
// D[n][bl] = A2t[n][m] . tsb[bl][m];  128x128 tile, BK=32, 4 waves (2x2), acc[4][4]
__global__ __launch_bounds__(256) void k4_att(const unsigned short* __restrict__ A2t,
                                              const unsigned short* __restrict__ tsb,
                                              const float* __restrict__ abias,
                                              const float* __restrict__ probs,
                                              unsigned short* __restrict__ P) {
    const int n0  = blockIdx.x * 128;
    const int bl0 = blockIdx.y * 128;
    const int t = threadIdx.x;
    const int lane = t & 63, w = t >> 6;
    const int wr = w >> 1, wc = w & 1;
    const int c = lane & 15, g = lane >> 4;

    __shared__ unsigned short a_l[128 * 32];
    __shared__ unsigned short b_l[128 * 32];
    __shared__ float ab_l[128];
    __shared__ float pb_l[128];

    if (t < 128) {
        ab_l[t] = abias[n0 + t];
        pb_l[t] = probs[(size_t)(bl0 + t) * C_ + (n0 >> 7)];
    }

    const int srow = t >> 1, soff = (t & 1) * 16;   // staging: 16 bf16 per thread per tile
    const unsigned short* gA = A2t + (size_t)(n0 + srow) * DM + soff;
    const unsigned short* gB = tsb + (size_t)(bl0 + srow) * DM + soff;

    f32x4 acc[4][4] = {};
    uint4 ra0, ra1, rb0, rb1;

    ra0 = *reinterpret_cast<const uint4*>(gA);
    ra1 = *reinterpret_cast<const uint4*>(gA + 8);
    rb0 = *reinterpret_cast<const uint4*>(gB);
    rb1 = *reinterpret_cast<const uint4*>(gB + 8);

    for (int kt = 0; kt < 8; ++kt) {
        __syncthreads();
        *reinterpret_cast<uint4*>(&a_l[t * 16])     = ra0;
        *reinterpret_cast<uint4*>(&a_l[t * 16 + 8]) = ra1;
        *reinterpret_cast<uint4*>(&b_l[t * 16])     = rb0;
        *reinterpret_cast<uint4*>(&b_l[t * 16 + 8]) = rb1;
        __syncthreads();
        if (kt < 7) {
            ra0 = *reinterpret_cast<const uint4*>(gA + (kt + 1) * 32);
            ra1 = *reinterpret_cast<const uint4*>(gA + (kt + 1) * 32 + 8);
            rb0 = *reinterpret_cast<const uint4*>(gB + (kt + 1) * 32);
            rb1 = *reinterpret_cast<const uint4*>(gB + (kt + 1) * 32 + 8);
        }
        bf16x8 af[4], bfr[4];
#pragma unroll
        for (int a = 0; a < 4; ++a)
            af[a] = *reinterpret_cast<const bf16x8*>(&a_l[(wr * 64 + a * 16 + c) * 32 + g * 8]);
#pragma unroll
        for (int b = 0; b < 4; ++b)
            bfr[b] = *reinterpret_cast<const bf16x8*>(&b_l[(wc * 64 + b * 16 + c) * 32 + g * 8]);
#pragma unroll
        for (int a = 0; a < 4; ++a)
#pragma unroll
            for (int b = 0; b < 4; ++b)
                acc[a][b] = __builtin_amdgcn_mfma_f32_16x16x32_bf16(af[a], bfr[b], acc[a][b], 0, 0, 0);
    }

    // epilogue: z = TEMP*(acc+abias); softmax over the 16 rows of each frag; scale by prob; write bf16
#pragma unroll
    for (int a = 0; a < 4; ++a) {
        const int nbase = wr * 64 + a * 16 + g * 4;
#pragma unroll
        for (int b = 0; b < 4; ++b) {
            const int bll = wc * 64 + b * 16 + c;
            float z[4], mx = -1e30f;
#pragma unroll
            for (int i = 0; i < 4; ++i) {
                z[i] = TEMPF * (acc[a][b][i] + ab_l[nbase + i]);
                mx = fmaxf(mx, z[i]);
            }
            mx = fmaxf(mx, __shfl_xor(mx, 16));
            mx = fmaxf(mx, __shfl_xor(mx, 32));
            float s = 0.f;
#pragma unroll
            for (int i = 0; i < 4; ++i) { z[i] = __expf(z[i] - mx); s += z[i]; }
            s += __shfl_xor(s, 16);
            s += __shfl_xor(s, 32);
            const float pv = pb_l[bll] / s;
            uint2 o;
            o.x = f2bf(z[0] * pv) | ((unsigned)f2bf(z[1] * pv) << 16);
            o.y = f2bf(z[2] * pv) | ((unsigned)f2bf(z[3] * pv) << 16);
            *reinterpret_cast<uint2*>(P + (size_t)(bl0 + bll) * LDP + n0 + nbase) = o;
        }
    }
}

// ---------------------------------------------------------------- K5: part[ks] = P(blx(2048|2080)) @ VWt^T
// M=bl (BM=64), N=e (BN=128), K split in 2; 4 waves (2x2), wave 32x64, acc[2][4]
__global__ __launch_bounds__(256) void k5_out(const unsigned short* __restrict__ P,
                                              const unsigned short* __restrict__ VWt,
                                              float* __restrict__ part) {
    const int bl0 = blockIdx.x * 64;
    const int e0  = blockIdx.y * 128;
    const int ks  = blockIdx.z;
    const int t = threadIdx.x;
    const int lane = t & 63, w = t >> 6;
    const int wr = w >> 1, wc = w & 1;
    const int c = lane & 15, g = lane >> 4;

    __shared__ unsigned short a_l[64 * 32];
    __shared__ unsigned short b_l[128 * 32];

    const int nstart = ks * 2048;
    const int nsteps = 64 + ks;        // ks1 covers the 32 bias-fold columns too

    const int arow = t >> 2, aoff = (t & 3) * 8;    // A: 8 bf16 per thread
    const int brow = t >> 1, boff = (t & 1) * 16;   // B: 16 bf16 per thread
    const unsigned short* gA = P   + (size_t)(bl0 + arow) * LDP + nstart + aoff;
    const unsigned short* gB = VWt + (size_t)(e0 + brow) * LDP + nstart + boff;

    f32x4 acc[2][4] = {};
    uint4 ra, rb0, rb1;
    ra  = *reinterpret_cast<const uint4*>(gA);
    rb0 = *reinterpret_cast<const uint4*>(gB);
    rb1 = *reinterpret_cast<const uint4*>(gB + 8);

    for (int kt = 0; kt < nsteps; ++kt) {
        __syncthreads();
        *reinterpret_cast<uint4*>(&a_l[t * 8])      = ra;
        *reinterpret_cast<uint4*>(&b_l[t * 16])     = rb0;
        *reinterpret_cast<uint4*>(&b_l[t * 16 + 8]) = rb1;
        __syncthreads();
        if (kt + 1 < nsteps) {
            ra  = *reinterpret_cast<const uint4*>(gA + (kt + 1) * 32);
            rb0 = *reinterpret_cast<const uint4*>(gB + (kt + 1) * 32);
            rb1 = *reinterpret_cast<const uint4*>(gB + (kt + 1) * 32 + 8);
        }
        bf16x8 af[2], bfr[4];
#pragma unroll
        for (int a = 0; a < 2; ++a)
            af[a] = *reinterpret_cast<const bf16x8*>(&a_l[(wr * 32 + a * 16 + c) * 32 + g * 8]);
#pragma unroll
        for (int b = 0; b < 4; ++b)
            bfr[b] = *reinterpret_cast<const bf16x8*>(&b_l[(wc * 64 + b * 16 + c) * 32 + g * 8]);
#pragma unroll
        for (int a = 0; a < 2; ++a)
#pragma unroll
            for (int b = 0; b < 4; ++b)
                acc[a][b] = __builtin_amdgcn_mfma_f32_16x16x32_bf16(af[a], bfr[b], acc[a][b], 0, 0, 0);
    }

    float* pp = part + ((size_t)ks * BL + bl0) * E_ + e0;
#pragma unroll
    for (int a = 0; a < 2; ++a)
#pragma unroll
        for (int b = 0; b < 4; ++b)
#pragma unroll
            for (int i = 0; i < 4; ++i)
                pp[(size_t)(wr * 32 + a * 16 + g * 4 + i) * E_ + wc * 64 + b * 16 + c] = acc[a][b][i];
}

// ---------------------------------------------------------------- k6: out = part0 + part1
__global__ __launch_bounds__(256) void k6_red(const float* __restrict__ part,
                                              float* __restrict__ out) {
    const int idx = (blockIdx.x * 256 + threadIdx.x) * 4;
    float4 p0 = *reinterpret_cast<const float4*>(part + idx);
    float4 p1 = *reinterpret_cast<const float4*>(part + (size_t)BL * E_ + idx);
    float4 o = make_float4(p0.x + p1.x, p0.y + p1.y, p0.z + p1.z, p0.w + p1.w);
    *reinterpret_cast<float4*>(out + idx) = o;
}

// ----------------------------------------------------------------
extern "C" void kernel_launch(void* const* d_in, const int* in_sizes, int n_in,
                              void* d_out, int out_size, void* d_ws, size_t ws_size,
                              hipStream_t stream) {
    const float* topk  = (const float*)d_in[0];
    const float* ts    = (const float*)d_in[1];
    const float* probs = (const float*)d_in[2];
    const float* qp    = (const float*)d_in[3];
    const float* kp    = (const float*)d_in[4];
    const float* vp    = (const float*)d_in[5];
    const float* ow    = (const float*)d_in[6];
    const float* ob    = (const float*)d_in[7];
    float* out = (float*)d_out;

    char* wp = (char*)d_ws;
    float* kk            = (float*)wp;           wp += 524288;
    float* vv            = (float*)wp;           wp += 524288;
    float* ab            = (float*)wp;           wp += 16384;
    unsigned short* tsb  = (unsigned short*)wp;  wp += 2097152;
    unsigned short* A2t  = (unsigned short*)wp;  wp += 2097152;
    unsigned short* VWt  = (unsigned short*)wp;  wp += (size_t)E_ * LDP * 2;   // 6,340,608
    unsigned short* P    = (unsigned short*)wp;  wp += (size_t)BL * LDP * 2;   // 33,816,576
    float* part          = (float*)wp;           // 2 * 4096*768*4 = 25,165,824

    // k1 partials alias `part` (dead until k5 runs)
    float* partk = part;                 // 1,048,576 floats
    float* partv = part + 1048576;       // 1,048,576 floats

    k1_kv <<<dim3(32, 8),   256, 0, stream>>>(topk, kp, vp, partk, partv);
    k1r   <<<512,           256, 0, stream>>>(partk, partv, kp, vp, kk, vv);
    k0_cvt<<<1152,          256, 0, stream>>>(ts, probs, ob, tsb, P, VWt);
    k2_A  <<<dim3(32, 8),   256, 0, stream>>>(qp, kk, A2t, ab);
    k3_VW <<<dim3(32, 8),   768, 0, stream>>>(ow, vv, VWt);
    k4_att<<<dim3(32, 32),  256, 0, stream>>>(A2t, tsb, ab, probs, P);
    k5_out<<<dim3(64, 6, 2),256, 0, stream>>>(P, VWt, part);
    k6_red<<<3072,          256, 0, stream>>>(part, out);
}